// Round 12
// baseline (86.858 us; speedup 1.0000x reference)
//
#include <hip/hip_runtime.h>
#include <hip/hip_bf16.h>
#include <stdint.h>

typedef __attribute__((ext_vector_type(8))) short short8;
typedef __attribute__((ext_vector_type(4))) short short4v;
typedef __attribute__((ext_vector_type(4))) float f32x4;
typedef __attribute__((ext_vector_type(2))) unsigned int uint2v;

#define DD 512
#define TT 16   // tokens per block (4 waves cooperate)
#define TN 4096 // T
#define NB 8    // B

__device__ __forceinline__ unsigned short f2bf(float f){
  uint32_t u = __float_as_uint(f);
  u += 0x7FFFu + ((u >> 16) & 1u);
  return (unsigned short)(u >> 16);
}
__device__ __forceinline__ float bf2f(unsigned short h){
  return __uint_as_float(((uint32_t)h) << 16);
}

// ---------------- prep kernels (wide 16-way-split dots) ----------------

__global__ void prep_spk(const float* __restrict__ se, const float* __restrict__ We,
                         const float* __restrict__ be, const float* __restrict__ spos,
                         float* __restrict__ spk){
  int idx = blockIdx.x * 256 + threadIdx.x;   // 262144
  int sub = idx & 15; int out = idx >> 4;
  int b = out & 7, od = out >> 3;
  const float* wr = We + (size_t)od * DD + sub * 4;
  const float* sb = se + b * DD + sub * 4;
  float acc = 0.f;
#pragma unroll
  for (int i = 0; i < 8; i++){
    float4 w = *(const float4*)(wr + i * 64);
    float4 x = *(const float4*)(sb + i * 64);
    acc += w.x * x.x + w.y * x.y + w.z * x.z + w.w * x.w;
  }
  acc += __shfl_xor(acc, 1); acc += __shfl_xor(acc, 2);
  acc += __shfl_xor(acc, 4); acc += __shfl_xor(acc, 8);
  if (sub == 0) spk[b * 2048 + od] = fmaxf(acc + be[od], 0.f) + spos[od];
}

__global__ void prep_kv(const float* __restrict__ spk, const float* __restrict__ Wk,
                        const float* __restrict__ bk, const float* __restrict__ Wv,
                        const float* __restrict__ bv, float* __restrict__ kb,
                        float* __restrict__ vb){
  int idx = blockIdx.x * 256 + threadIdx.x;   // 262144
  int sub = idx & 15; int out = idx >> 4;
  int hd = out >> 5; int r = out & 31; int b = r >> 2, s = r & 3;
  const float* sp  = spk + (b * 4 + s) * DD + sub * 4;
  const float* wkr = Wk + (size_t)hd * DD + sub * 4;
  const float* wvr = Wv + (size_t)hd * DD + sub * 4;
  float ak = 0.f, av = 0.f;
#pragma unroll
  for (int i = 0; i < 8; i++){
    float4 x  = *(const float4*)(sp + i * 64);
    float4 wk = *(const float4*)(wkr + i * 64);
    float4 wv = *(const float4*)(wvr + i * 64);
    ak += x.x * wk.x + x.y * wk.y + x.z * wk.z + x.w * wk.w;
    av += x.x * wv.x + x.y * wv.y + x.z * wv.z + x.w * wv.w;
  }
  ak += __shfl_xor(ak, 1); ak += __shfl_xor(ak, 2);
  ak += __shfl_xor(ak, 4); ak += __shfl_xor(ak, 8);
  av += __shfl_xor(av, 1); av += __shfl_xor(av, 2);
  av += __shfl_xor(av, 4); av += __shfl_xor(av, 8);
  if (sub == 0){
    kb[(b * 4 + s) * DD + hd] = ak + bk[hd];
    vb[(b * 4 + s) * DD + hd] = av + bv[hd];
  }
}

// Lane-major fragment packing; m-part uses coalesced contiguous Wq row-slices.
__global__ void prep_mu(const float* __restrict__ kb, const float* __restrict__ vb,
                        const float* __restrict__ Wq, const float* __restrict__ bq,
                        const float* __restrict__ Wo, const float* __restrict__ bo,
                        const float* __restrict__ Wg1,
                        const float* __restrict__ glng, const float* __restrict__ glnb,
                        const float* __restrict__ bg1,
                        unsigned short* __restrict__ mS, unsigned short* __restrict__ uS,
                        float* __restrict__ cArr, unsigned short* __restrict__ wg1S,
                        float* __restrict__ e1, float* __restrict__ e2){
  int idx = blockIdx.x * 256 + threadIdx.x;     // 229760 total
  if (idx < 32768){
    int dc = idx & 127, j = (idx >> 7) & 31, b = idx >> 12;
    int h = j >> 2, s = j & 3;
    const int d0 = dc * 4;
    const float* kr = kb + (b * 4 + s) * DD + h * 64;
    const float* wqb = Wq + (size_t)(h * 64) * DD + d0;
    float4 acc = {0.f, 0.f, 0.f, 0.f};
#pragma unroll 8
    for (int dh = 0; dh < 64; ++dh){
      float4 w4 = *(const float4*)(wqb + (size_t)dh * DD);
      float kvv = kr[dh];
      acc.x += kvv * w4.x; acc.y += kvv * w4.y;
      acc.z += kvv * w4.z; acc.w += kvv * w4.w;
    }
    const int kt = d0 >> 5, kgp = (d0 >> 3) & 3, e0 = d0 & 7, half = j >> 4;
    unsigned short* dst = mS + (size_t)(b * 16 + kt) * 1024 + half * 512 +
                          (kgp * 16 + (j & 15)) * 8 + e0;
    short4v st;
    st[0] = (short)f2bf(acc.x); st[1] = (short)f2bf(acc.y);
    st[2] = (short)f2bf(acc.z); st[3] = (short)f2bf(acc.w);
    *(short4v*)dst = st;
  } else if (idx < 163840){
    int t = idx - 32768;
    int j = t & 31; int d = (t >> 5) & 511; int b = t >> 14;
    int h = j >> 2, s = j & 3;
    const float* vr = vb + (b * 4 + s) * DD + h * 64;
    const float* wo = Wo + (size_t)d * DD + h * 64;
    float acc = 0.f;
#pragma unroll 8
    for (int dh = 0; dh < 64; dh += 4){
      float4 v4 = *(const float4*)(vr + dh);
      float4 w4 = *(const float4*)(wo + dh);
      acc += v4.x * w4.x + v4.y * w4.y + v4.z * w4.z + v4.w * w4.w;
    }
    int nc = d >> 7, nt = (d >> 4) & 7, r16p = d & 15;
    int kgp = j >> 3, e = j & 7;
    uS[(size_t)(b * 32 + nc * 8 + nt) * 512 + (kgp * 16 + r16p) * 8 + e] =
        f2bf(acc + bo[d] * 0.125f);
  } else if (idx < 229376){
    int t = idx - 163840;               // t = col*512 + d
    int col = t >> 9, d = t & 511;
    int nt = col >> 4, c16 = col & 15;
    int kt = d >> 5, kgp = (d >> 3) & 3, e = d & 7;
    wg1S[(size_t)(nt * 16 + kt) * 512 + (kgp * 16 + c16) * 8 + e] = f2bf(Wg1[t] * glng[d]);
  } else if (idx < 229632){
    int t = idx - 229376; int j = t & 31, b = t >> 5;
    int h = j >> 2, s = j & 3;
    const float* kr = kb + (b * 4 + s) * DD + h * 64;
    const float* bqp = bq + h * 64;
    float acc = 0.f;
    for (int dh = 0; dh < 64; dh++) acc += bqp[dh] * kr[dh];
    cArr[b * 32 + j] = acc;
  } else if (idx < 229760){
    int col = idx - 229632;
    const float* wr = Wg1 + (size_t)col * DD;
    float a1 = 0.f, a2 = 0.f;
    for (int d = 0; d < DD; d += 4){
      float4 w  = *(const float4*)(wr + d);
      float4 gm = *(const float4*)(glng + d);
      float4 bt = *(const float4*)(glnb + d);
      a1 += w.x * gm.x + w.y * gm.y + w.z * gm.z + w.w * gm.w;
      a2 += w.x * bt.x + w.y * bt.y + w.z * bt.z + w.w * bt.w;
    }
    e1[col] = a1; e2[col] = a2 + bg1[col];
  }
}

// ---------------- main fused kernel: 4 waves, 16 tokens, 8 blocks/CU ----------------

__global__ __launch_bounds__(256, 8) void fused_main(
    const float* __restrict__ xin,
    const float* __restrict__ e1v, const float* __restrict__ e2v,
    const float* __restrict__ wg2v, const float* __restrict__ bg2v,
    const float* __restrict__ lng, const float* __restrict__ lnb,
    const unsigned short* __restrict__ mS,
    const unsigned short* __restrict__ uS,
    const float* __restrict__ cArr,
    const unsigned short* __restrict__ wg1S,
    float* __restrict__ outF, float* __restrict__ outAW, float* __restrict__ outG)
{
  __shared__ __align__(16) unsigned short Yb[TT * DD];   // 16 KB x/y bf16 (swizzled)
  __shared__ __align__(16) unsigned short Wl[TT * 32];
  __shared__ float smu[TT], srs[TT];
  __shared__ float aws[2][TT * 4];
  __shared__ float gp[4][TT];
  __shared__ float pp[4][TT], qq[4][TT];

  const int tid  = threadIdx.x;
  const int w    = tid >> 6;
  const int lane = tid & 63;
  const int r16  = lane & 15;
  const int kg   = lane >> 4;
  const int bb   = blockIdx.x >> 8;
  const int t0   = (blockIdx.x & 255) << 4;
  const size_t rowbase = (size_t)bb * TN + t0;
  const int swzS = (r16 & 7) << 3;

  // ---- phase 0: issue all 8 x loads, convert + LN stats ----
  const float* xbase = xin + rowbase * DD;
  float4 xl[8];
#pragma unroll
  for (int i = 0; i < 4; ++i)
#pragma unroll
    for (int h2 = 0; h2 < 2; ++h2)
      xl[i * 2 + h2] = *(const float4*)(xbase + (w * 4 + i) * DD + h2 * 256 + lane * 4);

#pragma unroll
  for (int i = 0; i < 4; ++i){
    const int rr = w * 4 + i;
    const int swz = (rr & 7) << 3;
    float s = 0.f, q = 0.f;
#pragma unroll
    for (int h2 = 0; h2 < 2; ++h2){
      float4 v4 = xl[i * 2 + h2];
      short4v pk;
      pk[0] = (short)f2bf(v4.x); pk[1] = (short)f2bf(v4.y);
      pk[2] = (short)f2bf(v4.z); pk[3] = (short)f2bf(v4.w);
      s += (v4.x + v4.y) + (v4.z + v4.w);
      q += (v4.x*v4.x + v4.y*v4.y) + (v4.z*v4.z + v4.w*v4.w);
      const int col = h2 * 256 + lane * 4;
      *(short4v*)&Yb[rr * DD + (col ^ swz)] = pk;
    }
#pragma unroll
    for (int off = 1; off < 64; off <<= 1){ s += __shfl_xor(s, off); q += __shfl_xor(q, off); }
    if (lane == 0){
      const float mu = s * (1.f/DD);
      smu[rr] = mu;
      srs[rr] = rsqrtf(q * (1.f/DD) - mu*mu + 1e-5f);
    }
  }
  __syncthreads();  // S1

  // ---- phase 1: waves 0,1: score half + 2 gate nt; waves 2,3: 2 gate nt ----
  const int half = w & 1;
  const int nt0  = w * 2;
  const unsigned short* mSp  = mS + (size_t)bb * 16384 + half * 512 + lane * 8;
  const unsigned short* wgp0 = wg1S + (size_t)(nt0 * 16) * 512 + lane * 8;
  const unsigned short* wgp1 = wgp0 + (size_t)16 * 512;
  f32x4 sa = {0.f,0.f,0.f,0.f}, ga0 = {0.f,0.f,0.f,0.f}, ga1 = {0.f,0.f,0.f,0.f};
  if (w < 2){
#pragma unroll
    for (int kt = 0; kt < 16; ++kt){
      short8 af = *(const short8*)&Yb[r16 * DD + ((kt*32 + kg*8) ^ swzS)];
      short8 b0 = *(const short8*)(mSp + (size_t)kt * 1024);
      sa  = __builtin_amdgcn_mfma_f32_16x16x32_bf16(af, b0, sa, 0, 0, 0);
      short8 wf0 = *(const short8*)(wgp0 + (size_t)kt * 512);
      ga0 = __builtin_amdgcn_mfma_f32_16x16x32_bf16(wf0, af, ga0, 0, 0, 0);
      short8 wf1 = *(const short8*)(wgp1 + (size_t)kt * 512);
      ga1 = __builtin_amdgcn_mfma_f32_16x16x32_bf16(wf1, af, ga1, 0, 0, 0);
    }
  } else {
#pragma unroll
    for (int kt = 0; kt < 16; ++kt){
      short8 af = *(const short8*)&Yb[r16 * DD + ((kt*32 + kg*8) ^ swzS)];
      short8 wf0 = *(const short8*)(wgp0 + (size_t)kt * 512);
      ga0 = __builtin_amdgcn_mfma_f32_16x16x32_bf16(wf0, af, ga0, 0, 0, 0);
      short8 wf1 = *(const short8*)(wgp1 + (size_t)kt * 512);
      ga1 = __builtin_amdgcn_mfma_f32_16x16x32_bf16(wf1, af, ga1, 0, 0, 0);
    }
  }

  // ---- early epilogue operand loads ----
  float4 e1c[2], e2c[2], w2c[2];
#pragma unroll
  for (int t = 0; t < 2; ++t){
    const int c4 = (nt0 + t) * 16 + kg * 4;
    e1c[t] = *(const float4*)(e1v + c4);
    e2c[t] = *(const float4*)(e2v + c4);
    w2c[t] = *(const float4*)(wg2v + c4);
  }
  float4 lgh[2], lbh[2];
#pragma unroll
  for (int h2 = 0; h2 < 2; ++h2){
    lgh[h2] = *(const float4*)(lng + h2*256 + lane*4);
    lbh[h2] = *(const float4*)(lnb + h2*256 + lane*4);
  }
  const float bg2s = bg2v[0];

  // ---- softmax epilogue (waves 0,1) ----
  if (w < 2){
    const float cv = cArr[bb*32 + half*16 + r16];
#pragma unroll
    for (int r = 0; r < 4; ++r){
      float s0 = (sa[r] + cv) * 0.125f;
      float mx = fmaxf(s0, __shfl_xor(s0, 1)); mx = fmaxf(mx, __shfl_xor(mx, 2));
      float e0 = __expf(s0 - mx);
      float d0 = e0; d0 += __shfl_xor(d0, 1); d0 += __shfl_xor(d0, 2);
      float wv = e0 / d0;
      float t = wv; t += __shfl_xor(t, 4); t += __shfl_xor(t, 8);
      const int rw = kg * 4 + r;
      Wl[rw * 32 + half * 16 + r16] = f2bf(wv);
      if ((lane & 12) == 0) aws[half][rw * 4 + (lane & 3)] = t;
    }
  }

  // ---- gate partial (all waves): thread owns token r16 ----
  {
    const float mu_t = smu[r16], rs_t = srs[r16];
    float part = 0.f;
#pragma unroll
    for (int t = 0; t < 2; ++t){
      const f32x4 ga = t ? ga1 : ga0;
      float ea[4] = {e1c[t].x, e1c[t].y, e1c[t].z, e1c[t].w};
      float eb[4] = {e2c[t].x, e2c[t].y, e2c[t].z, e2c[t].w};
      float wc[4] = {w2c[t].x, w2c[t].y, w2c[t].z, w2c[t].w};
#pragma unroll
      for (int r = 0; r < 4; ++r){
        float gv = rs_t * (ga[r] - mu_t * ea[r]) + eb[r];
        part += fmaxf(gv, 0.f) * wc[r];
      }
    }
    part += __shfl_xor(part, 16); part += __shfl_xor(part, 32);
    if (kg == 0) gp[w][r16] = part;
  }
  __syncthreads();  // S2

  // ---- outAW finalize (wave 2) ----
  if (w == 2){
    const int tok = lane >> 2;
    const int si = lane & 3;
    const float val = (aws[0][tok*4 + si] + aws[1][tok*4 + si]) * 0.125f;
    outAW[(rowbase + tok) * 4 + si] = val;
  }
  // ---- gate finalize ----
  float g_reg;
  {
    const float gs = gp[0][r16] + gp[1][r16] + gp[2][r16] + gp[3][r16];
    g_reg = 1.f / (1.f + __expf(-(gs + bg2s)));
    if (w == 3 && kg == 0) outG[rowbase + r16] = g_reg;
  }

  // ---- phase 3: ATT column-quarter nc = w; residual; y -> Yb ----
  short8 awf = *(const short8*)&Wl[r16 * 32 + kg * 8];
  const unsigned short* uSp = uS + (size_t)bb * 16384 + (size_t)(w * 8) * 512 + lane * 8;
  f32x4 acc[8];
#pragma unroll
  for (int nt = 0; nt < 8; ++nt){
    short8 uf = *(const short8*)(uSp + (size_t)nt * 512);
    f32x4 z = {0.f,0.f,0.f,0.f};
    acc[nt] = __builtin_amdgcn_mfma_f32_16x16x32_bf16(uf, awf, z, 0, 0, 0);
  }
  float psum = 0.f, psq = 0.f;
#pragma unroll
  for (int nt = 0; nt < 8; ++nt){
    const int c4 = w * 128 + nt * 16 + kg * 4;
    const int idx = r16 * DD + (c4 ^ swzS);
    uint2v xch = *(const uint2v*)&Yb[idx];
    unsigned int lo = xch[0], hi = xch[1];
    float y0 = bf2f((unsigned short)(lo & 0xffffu)) + g_reg * acc[nt][0];
    float y1 = bf2f((unsigned short)(lo >> 16))     + g_reg * acc[nt][1];
    float y2 = bf2f((unsigned short)(hi & 0xffffu)) + g_reg * acc[nt][2];
    float y3 = bf2f((unsigned short)(hi >> 16))     + g_reg * acc[nt][3];
    psum += (y0 + y1) + (y2 + y3);
    psq  += (y0*y0 + y1*y1) + (y2*y2 + y3*y3);
    uint2v yp;
    yp[0] = (unsigned)f2bf(y0) | ((unsigned)f2bf(y1) << 16);
    yp[1] = (unsigned)f2bf(y2) | ((unsigned)f2bf(y3) << 16);
    *(uint2v*)&Yb[idx] = yp;
  }
  psum += __shfl_xor(psum, 16); psum += __shfl_xor(psum, 32);
  psq  += __shfl_xor(psq, 16);  psq  += __shfl_xor(psq, 32);
  if (kg == 0){ pp[w][r16] = psum; qq[w][r16] = psq; }
  __syncthreads();  // S3

  // ---- phase 4: final LN + contiguous fp32 stores ----
#pragma unroll
  for (int i = 0; i < 4; ++i){
    const int rr = w * 4 + i;
    const float sm = pp[0][rr] + pp[1][rr] + pp[2][rr] + pp[3][rr];
    const float sq = qq[0][rr] + qq[1][rr] + qq[2][rr] + qq[3][rr];
    const float mu2 = sm * (1.f/DD);
    const float rs2 = rsqrtf(sq * (1.f/DD) - mu2*mu2 + 1e-5f);
    const int swz = (rr & 7) << 3;
#pragma unroll
    for (int h2 = 0; h2 < 2; ++h2){
      const int col = h2 * 256 + lane * 4;
      short4v yv = *(const short4v*)&Yb[rr * DD + (col ^ swz)];
      float la[4] = {lgh[h2].x, lgh[h2].y, lgh[h2].z, lgh[h2].w};
      float lb4[4] = {lbh[h2].x, lbh[h2].y, lbh[h2].z, lbh[h2].w};
      float4 o;
      o.x = (bf2f((unsigned short)yv[0]) - mu2) * rs2 * la[0] + lb4[0];
      o.y = (bf2f((unsigned short)yv[1]) - mu2) * rs2 * la[1] + lb4[1];
      o.z = (bf2f((unsigned short)yv[2]) - mu2) * rs2 * la[2] + lb4[2];
      o.w = (bf2f((unsigned short)yv[3]) - mu2) * rs2 * la[3] + lb4[3];
      *(float4*)(outF + (rowbase + rr) * DD + col) = o;
    }
  }
}

// ---------------- launch ----------------

extern "C" void kernel_launch(void* const* d_in, const int* in_sizes, int n_in,
                              void* d_out, int out_size, void* d_ws, size_t ws_size,
                              hipStream_t stream)
{
  const float* token = (const float*)d_in[0];
  const float* semb  = (const float*)d_in[1];
  const float* We    = (const float*)d_in[2];
  const float* be    = (const float*)d_in[3];
  const float* spos  = (const float*)d_in[4];
  const float* Wq    = (const float*)d_in[5];
  const float* bq    = (const float*)d_in[6];
  const float* Wk    = (const float*)d_in[7];
  const float* bk    = (const float*)d_in[8];
  const float* Wv    = (const float*)d_in[9];
  const float* bv    = (const float*)d_in[10];
  const float* Wo    = (const float*)d_in[11];
  const float* bo    = (const float*)d_in[12];
  const float* glng  = (const float*)d_in[13];
  const float* glnb  = (const float*)d_in[14];
  const float* Wg1   = (const float*)d_in[15];
  const float* bg1   = (const float*)d_in[16];
  const float* Wg2   = (const float*)d_in[17];
  const float* bg2   = (const float*)d_in[18];
  const float* lng   = (const float*)d_in[19];
  const float* lnb   = (const float*)d_in[20];

  char* ws = (char*)d_ws;
  float* e1             = (float*)(ws + 0);        // 512 B (spk region reused)
  float* e2             = (float*)(ws + 512);
  float* spk            = (float*)(ws + 0);        // 64 KB (dead before e1/e2 written)
  float* kb             = (float*)(ws + 65536);
  float* vb             = (float*)(ws + 131072);
  unsigned short* mS    = (unsigned short*)(ws + 196608);
  unsigned short* uS    = (unsigned short*)(ws + 458752);
  float* cArr           = (float*)(ws + 720896);
  unsigned short* wg1S  = (unsigned short*)(ws + 721920);

  float* outF  = (float*)d_out;
  float* outAW = outF + (size_t)NB * TN * DD;
  float* outG  = outAW + (size_t)NB * TN * 4;

  prep_spk<<<dim3(1024), dim3(256), 0, stream>>>(semb, We, be, spos, spk);
  prep_kv<<<dim3(1024), dim3(256), 0, stream>>>(spk, Wk, bk, Wv, bv, kb, vb);
  prep_mu<<<dim3(898), dim3(256), 0, stream>>>(kb, vb, Wq, bq, Wo, bo, Wg1, glng, glnb, bg1,
                                               mS, uS, cArr, wg1S, e1, e2);
  fused_main<<<dim3(NB * TN / TT), dim3(256), 0, stream>>>(
      token, e1, e2, Wg2, bg2, lng, lnb,
      mS, uS, cArr, wg1S, outF, outAW, outG);
}

// Round 13
// 83.065 us; speedup vs baseline: 1.0457x; 1.0457x over previous
//
#include <hip/hip_runtime.h>
#include <hip/hip_bf16.h>
#include <stdint.h>

typedef __attribute__((ext_vector_type(8))) short short8;
typedef __attribute__((ext_vector_type(4))) short short4v;
typedef __attribute__((ext_vector_type(4))) float f32x4;
typedef __attribute__((ext_vector_type(2))) unsigned int uint2v;

#define DD 512
#define TT 16   // tokens per block (4 waves cooperate)
#define TN 4096 // T
#define NB 8    // B

__device__ __forceinline__ unsigned short f2bf(float f){
  uint32_t u = __float_as_uint(f);
  u += 0x7FFFu + ((u >> 16) & 1u);
  return (unsigned short)(u >> 16);
}
__device__ __forceinline__ float bf2f(unsigned short h){
  return __uint_as_float(((uint32_t)h) << 16);
}
// async global -> LDS, 16 B per lane; lds base must be wave-uniform
__device__ __forceinline__ void gll16(const void* g, void* l){
  __builtin_amdgcn_global_load_lds(
      (const __attribute__((address_space(1))) unsigned int*)g,
      (__attribute__((address_space(3))) unsigned int*)l, 16, 0, 0);
}

// ---------------- prep kernels ----------------

// spk + (input-only) wg1S / e1 / e2
__global__ void prep_spk(const float* __restrict__ se, const float* __restrict__ We,
                         const float* __restrict__ be, const float* __restrict__ spos,
                         const float* __restrict__ Wg1,
                         const float* __restrict__ glng, const float* __restrict__ glnb,
                         const float* __restrict__ bg1,
                         float* __restrict__ spk, unsigned short* __restrict__ wg1S,
                         float* __restrict__ e1, float* __restrict__ e2){
  int idx = blockIdx.x * 256 + threadIdx.x;   // 327808 used
  if (idx < 262144){
    int sub = idx & 15; int out = idx >> 4;
    int b = out & 7, od = out >> 3;
    const float* wr = We + (size_t)od * DD + sub * 4;
    const float* sb = se + b * DD + sub * 4;
    float acc = 0.f;
#pragma unroll
    for (int i = 0; i < 8; i++){
      float4 w = *(const float4*)(wr + i * 64);
      float4 x = *(const float4*)(sb + i * 64);
      acc += w.x * x.x + w.y * x.y + w.z * x.z + w.w * x.w;
    }
    acc += __shfl_xor(acc, 1); acc += __shfl_xor(acc, 2);
    acc += __shfl_xor(acc, 4); acc += __shfl_xor(acc, 8);
    if (sub == 0) spk[b * 2048 + od] = fmaxf(acc + be[od], 0.f) + spos[od];
  } else if (idx < 327680){
    int t = idx - 262144;               // t = col*512 + d
    int col = t >> 9, d = t & 511;
    int nt = col >> 4, c16 = col & 15;
    int kt = d >> 5, kgp = (d >> 3) & 3, e = d & 7;
    wg1S[(size_t)(nt * 16 + kt) * 512 + (kgp * 16 + c16) * 8 + e] = f2bf(Wg1[t] * glng[d]);
  } else if (idx < 327808){
    int col = idx - 327680;
    const float* wr = Wg1 + (size_t)col * DD;
    float a1 = 0.f, a2 = 0.f;
    for (int d = 0; d < DD; d += 4){
      float4 w  = *(const float4*)(wr + d);
      float4 gm = *(const float4*)(glng + d);
      float4 bt = *(const float4*)(glnb + d);
      a1 += w.x * gm.x + w.y * gm.y + w.z * gm.z + w.w * gm.w;
      a2 += w.x * bt.x + w.y * bt.y + w.z * bt.z + w.w * bt.w;
    }
    e1[col] = a1; e2[col] = a2 + bg1[col];
  }
}

__global__ void prep_kv(const float* __restrict__ spk, const float* __restrict__ Wk,
                        const float* __restrict__ bk, const float* __restrict__ Wv,
                        const float* __restrict__ bv, float* __restrict__ kb,
                        float* __restrict__ vb){
  int idx = blockIdx.x * 256 + threadIdx.x;   // 262144
  int sub = idx & 15; int out = idx >> 4;
  int hd = out >> 5; int r = out & 31; int b = r >> 2, s = r & 3;
  const float* sp  = spk + (b * 4 + s) * DD + sub * 4;
  const float* wkr = Wk + (size_t)hd * DD + sub * 4;
  const float* wvr = Wv + (size_t)hd * DD + sub * 4;
  float ak = 0.f, av = 0.f;
#pragma unroll
  for (int i = 0; i < 8; i++){
    float4 x  = *(const float4*)(sp + i * 64);
    float4 wk = *(const float4*)(wkr + i * 64);
    float4 wv = *(const float4*)(wvr + i * 64);
    ak += x.x * wk.x + x.y * wk.y + x.z * wk.z + x.w * wk.w;
    av += x.x * wv.x + x.y * wv.y + x.z * wv.z + x.w * wv.w;
  }
  ak += __shfl_xor(ak, 1); ak += __shfl_xor(ak, 2);
  ak += __shfl_xor(ak, 4); ak += __shfl_xor(ak, 8);
  av += __shfl_xor(av, 1); av += __shfl_xor(av, 2);
  av += __shfl_xor(av, 4); av += __shfl_xor(av, 8);
  if (sub == 0){
    kb[(b * 4 + s) * DD + hd] = ak + bk[hd];
    vb[(b * 4 + s) * DD + hd] = av + bv[hd];
  }
}

// mS / uS / cArr (lane-major fragment packing)
__global__ void prep_mu(const float* __restrict__ kb, const float* __restrict__ vb,
                        const float* __restrict__ Wq, const float* __restrict__ bq,
                        const float* __restrict__ Wo, const float* __restrict__ bo,
                        unsigned short* __restrict__ mS, unsigned short* __restrict__ uS,
                        float* __restrict__ cArr){
  int idx = blockIdx.x * 256 + threadIdx.x;     // 164096 used
  if (idx < 32768){
    int dc = idx & 127, j = (idx >> 7) & 31, b = idx >> 12;
    int h = j >> 2, s = j & 3;
    const int d0 = dc * 4;
    const float* kr = kb + (b * 4 + s) * DD + h * 64;
    const float* wqb = Wq + (size_t)(h * 64) * DD + d0;
    float4 acc = {0.f, 0.f, 0.f, 0.f};
#pragma unroll 8
    for (int dh = 0; dh < 64; ++dh){
      float4 w4 = *(const float4*)(wqb + (size_t)dh * DD);
      float kvv = kr[dh];
      acc.x += kvv * w4.x; acc.y += kvv * w4.y;
      acc.z += kvv * w4.z; acc.w += kvv * w4.w;
    }
    const int kt = d0 >> 5, kgp = (d0 >> 3) & 3, e0 = d0 & 7, half = j >> 4;
    unsigned short* dst = mS + (size_t)(b * 16 + kt) * 1024 + half * 512 +
                          (kgp * 16 + (j & 15)) * 8 + e0;
    short4v st;
    st[0] = (short)f2bf(acc.x); st[1] = (short)f2bf(acc.y);
    st[2] = (short)f2bf(acc.z); st[3] = (short)f2bf(acc.w);
    *(short4v*)dst = st;
  } else if (idx < 163840){
    int t = idx - 32768;
    int j = t & 31; int d = (t >> 5) & 511; int b = t >> 14;
    int h = j >> 2, s = j & 3;
    const float* vr = vb + (b * 4 + s) * DD + h * 64;
    const float* wo = Wo + (size_t)d * DD + h * 64;
    float acc = 0.f;
#pragma unroll 8
    for (int dh = 0; dh < 64; dh += 4){
      float4 v4 = *(const float4*)(vr + dh);
      float4 w4 = *(const float4*)(wo + dh);
      acc += v4.x * w4.x + v4.y * w4.y + v4.z * w4.z + v4.w * w4.w;
    }
    int nc = d >> 7, nt = (d >> 4) & 7, r16p = d & 15;
    int kgp = j >> 3, e = j & 7;
    uS[(size_t)(b * 32 + nc * 8 + nt) * 512 + (kgp * 16 + r16p) * 8 + e] =
        f2bf(acc + bo[d] * 0.125f);
  } else if (idx < 164096){
    int t = idx - 163840; int j = t & 31, b = t >> 5;
    int h = j >> 2, s = j & 3;
    const float* kr = kb + (b * 4 + s) * DD + h * 64;
    const float* bqp = bq + h * 64;
    float acc = 0.f;
    for (int dh = 0; dh < 64; dh++) acc += bqp[dh] * kr[dh];
    cArr[b * 32 + j] = acc;
  }
}

// ---------------- main fused kernel: async-staged phase-1 pipeline ----------------

__global__ __launch_bounds__(256, 2) void fused_main(
    const float* __restrict__ xin,
    const float* __restrict__ e1v, const float* __restrict__ e2v,
    const float* __restrict__ wg2v, const float* __restrict__ bg2v,
    const float* __restrict__ lng, const float* __restrict__ lnb,
    const unsigned short* __restrict__ mS,
    const unsigned short* __restrict__ uS,
    const float* __restrict__ cArr,
    const unsigned short* __restrict__ wg1S,
    float* __restrict__ outF, float* __restrict__ outAW, float* __restrict__ outG)
{
  __shared__ __align__(16) unsigned short Yb[TT * DD];   // 16 KB x/y bf16 (swizzled)
  __shared__ __align__(16) unsigned short SB[20480];     // 40 KB weight stage (2 buf x 2 kt)
  __shared__ __align__(16) unsigned short Wl[TT * 32];
  __shared__ float smu[TT], srs[TT];
  __shared__ float aws[2][TT * 4];
  __shared__ float gp[4][TT];
  __shared__ float pp[4][TT], qq[4][TT];

  const int tid  = threadIdx.x;
  const int w    = tid >> 6;
  const int lane = tid & 63;
  const int r16  = lane & 15;
  const int kg   = lane >> 4;
  const int bb   = blockIdx.x >> 8;
  const int t0   = (blockIdx.x & 255) << 4;
  const size_t rowbase = (size_t)bb * TN + t0;
  const int swzS = (r16 & 7) << 3;

  const int half = w & 1;
  const int nt0  = w * 2;
  // per-lane global sources (lane-major layouts: wave = contiguous 1 KB)
  const unsigned short* mG   = mS + (size_t)bb * 16384 + half * 512 + lane * 8;   // +kt*1024
  const unsigned short* wgp0 = wg1S + (size_t)(nt0 * 16) * 512 + lane * 8;        // +kt*512
  const unsigned short* wgp1 = wgp0 + (size_t)16 * 512;
  // wave strip offset in SB (shorts): per-kt strip = 5120 shorts (10 KB)
  const int woff = (w < 2) ? w * 1536 : 3072 + (w - 2) * 1024;

  // ---- stage chunk 0 (kt 0,1) async into SB slot 0 ----
  {
#pragma unroll
    for (int ktc = 0; ktc < 2; ++ktc){
      unsigned short* lb = &SB[ktc * 5120 + woff];
      const int kt = ktc;
      if (w < 2){
        gll16(mG   + (size_t)kt * 1024, lb);
        gll16(wgp0 + (size_t)kt * 512,  lb + 512);
        gll16(wgp1 + (size_t)kt * 512,  lb + 1024);
      } else {
        gll16(wgp0 + (size_t)kt * 512,  lb);
        gll16(wgp1 + (size_t)kt * 512,  lb + 512);
      }
    }
  }

  // ---- phase 0: issue all 8 x loads, convert + LN stats ----
  const float* xbase = xin + rowbase * DD;
  float4 xl[8];
#pragma unroll
  for (int i = 0; i < 4; ++i)
#pragma unroll
    for (int h2 = 0; h2 < 2; ++h2)
      xl[i * 2 + h2] = *(const float4*)(xbase + (w * 4 + i) * DD + h2 * 256 + lane * 4);

#pragma unroll
  for (int i = 0; i < 4; ++i){
    const int rr = w * 4 + i;
    const int swz = (rr & 7) << 3;
    float s = 0.f, q = 0.f;
#pragma unroll
    for (int h2 = 0; h2 < 2; ++h2){
      float4 v4 = xl[i * 2 + h2];
      short4v pk;
      pk[0] = (short)f2bf(v4.x); pk[1] = (short)f2bf(v4.y);
      pk[2] = (short)f2bf(v4.z); pk[3] = (short)f2bf(v4.w);
      s += (v4.x + v4.y) + (v4.z + v4.w);
      q += (v4.x*v4.x + v4.y*v4.y) + (v4.z*v4.z + v4.w*v4.w);
      const int col = h2 * 256 + lane * 4;
      *(short4v*)&Yb[rr * DD + (col ^ swz)] = pk;
    }
#pragma unroll
    for (int off = 1; off < 64; off <<= 1){ s += __shfl_xor(s, off); q += __shfl_xor(q, off); }
    if (lane == 0){
      const float mu = s * (1.f/DD);
      smu[rr] = mu;
      srs[rr] = rsqrtf(q * (1.f/DD) - mu*mu + 1e-5f);
    }
  }
  __syncthreads();  // S1: Yb ready AND chunk-0 weights staged

  // ---- phase 1: 2-phase pipeline over 8 chunks (2 kt each) ----
  f32x4 sa = {0.f,0.f,0.f,0.f}, ga0 = {0.f,0.f,0.f,0.f}, ga1 = {0.f,0.f,0.f,0.f};
#pragma unroll
  for (int c = 0; c < 8; ++c){
    if (c < 7){
      const int slot = ((c + 1) & 1) * 10240;
#pragma unroll
      for (int ktc = 0; ktc < 2; ++ktc){
        unsigned short* lb = &SB[slot + ktc * 5120 + woff];
        const int kt = (c + 1) * 2 + ktc;
        if (w < 2){
          gll16(mG   + (size_t)kt * 1024, lb);
          gll16(wgp0 + (size_t)kt * 512,  lb + 512);
          gll16(wgp1 + (size_t)kt * 512,  lb + 1024);
        } else {
          gll16(wgp0 + (size_t)kt * 512,  lb);
          gll16(wgp1 + (size_t)kt * 512,  lb + 512);
        }
      }
    }
#pragma unroll
    for (int ktc = 0; ktc < 2; ++ktc){
      const int kt = c * 2 + ktc;
      const unsigned short* lb = &SB[(c & 1) * 10240 + ktc * 5120 + woff];
      short8 af = *(const short8*)&Yb[r16 * DD + ((kt*32 + kg*8) ^ swzS)];
      if (w < 2){
        short8 bm  = *(const short8*)&lb[lane * 8];
        short8 wf0 = *(const short8*)&lb[512 + lane * 8];
        short8 wf1 = *(const short8*)&lb[1024 + lane * 8];
        sa  = __builtin_amdgcn_mfma_f32_16x16x32_bf16(af, bm, sa, 0, 0, 0);
        ga0 = __builtin_amdgcn_mfma_f32_16x16x32_bf16(wf0, af, ga0, 0, 0, 0);
        ga1 = __builtin_amdgcn_mfma_f32_16x16x32_bf16(wf1, af, ga1, 0, 0, 0);
      } else {
        short8 wf0 = *(const short8*)&lb[lane * 8];
        short8 wf1 = *(const short8*)&lb[512 + lane * 8];
        ga0 = __builtin_amdgcn_mfma_f32_16x16x32_bf16(wf0, af, ga0, 0, 0, 0);
        ga1 = __builtin_amdgcn_mfma_f32_16x16x32_bf16(wf1, af, ga1, 0, 0, 0);
      }
    }
    __syncthreads();  // chunk c+1 staged; slot c free for c+2
  }

  // ---- early epilogue operand loads ----
  float4 e1c[2], e2c[2], w2c[2];
#pragma unroll
  for (int t = 0; t < 2; ++t){
    const int c4 = (nt0 + t) * 16 + kg * 4;
    e1c[t] = *(const float4*)(e1v + c4);
    e2c[t] = *(const float4*)(e2v + c4);
    w2c[t] = *(const float4*)(wg2v + c4);
  }
  float4 lgh[2], lbh[2];
#pragma unroll
  for (int h2 = 0; h2 < 2; ++h2){
    lgh[h2] = *(const float4*)(lng + h2*256 + lane*4);
    lbh[h2] = *(const float4*)(lnb + h2*256 + lane*4);
  }
  const float bg2s = bg2v[0];

  // ---- softmax epilogue (waves 0,1) ----
  if (w < 2){
    const float cv = cArr[bb*32 + half*16 + r16];
#pragma unroll
    for (int r = 0; r < 4; ++r){
      float s0 = (sa[r] + cv) * 0.125f;
      float mx = fmaxf(s0, __shfl_xor(s0, 1)); mx = fmaxf(mx, __shfl_xor(mx, 2));
      float e0 = __expf(s0 - mx);
      float d0 = e0; d0 += __shfl_xor(d0, 1); d0 += __shfl_xor(d0, 2);
      float wv = e0 / d0;
      float t = wv; t += __shfl_xor(t, 4); t += __shfl_xor(t, 8);
      const int rw = kg * 4 + r;
      Wl[rw * 32 + half * 16 + r16] = f2bf(wv);
      if ((lane & 12) == 0) aws[half][rw * 4 + (lane & 3)] = t;
    }
  }

  // ---- gate partial (all waves): thread owns token r16 ----
  {
    const float mu_t = smu[r16], rs_t = srs[r16];
    float part = 0.f;
#pragma unroll
    for (int t = 0; t < 2; ++t){
      const f32x4 ga = t ? ga1 : ga0;
      float ea[4] = {e1c[t].x, e1c[t].y, e1c[t].z, e1c[t].w};
      float eb[4] = {e2c[t].x, e2c[t].y, e2c[t].z, e2c[t].w};
      float wc[4] = {w2c[t].x, w2c[t].y, w2c[t].z, w2c[t].w};
#pragma unroll
      for (int r = 0; r < 4; ++r){
        float gv = rs_t * (ga[r] - mu_t * ea[r]) + eb[r];
        part += fmaxf(gv, 0.f) * wc[r];
      }
    }
    part += __shfl_xor(part, 16); part += __shfl_xor(part, 32);
    if (kg == 0) gp[w][r16] = part;
  }
  __syncthreads();  // S2

  // ---- outAW finalize (wave 2) ----
  if (w == 2){
    const int tok = lane >> 2;
    const int si = lane & 3;
    const float val = (aws[0][tok*4 + si] + aws[1][tok*4 + si]) * 0.125f;
    outAW[(rowbase + tok) * 4 + si] = val;
  }
  // ---- gate finalize ----
  float g_reg;
  {
    const float gs = gp[0][r16] + gp[1][r16] + gp[2][r16] + gp[3][r16];
    g_reg = 1.f / (1.f + __expf(-(gs + bg2s)));
    if (w == 3 && kg == 0) outG[rowbase + r16] = g_reg;
  }

  // ---- phase 3: ATT column-quarter nc = w; residual; y -> Yb ----
  short8 awf = *(const short8*)&Wl[r16 * 32 + kg * 8];
  const unsigned short* uSp = uS + (size_t)bb * 16384 + (size_t)(w * 8) * 512 + lane * 8;
  f32x4 acc[8];
#pragma unroll
  for (int nt = 0; nt < 8; ++nt){
    short8 uf = *(const short8*)(uSp + (size_t)nt * 512);
    f32x4 z = {0.f,0.f,0.f,0.f};
    acc[nt] = __builtin_amdgcn_mfma_f32_16x16x32_bf16(uf, awf, z, 0, 0, 0);
  }
  float psum = 0.f, psq = 0.f;
#pragma unroll
  for (int nt = 0; nt < 8; ++nt){
    const int c4 = w * 128 + nt * 16 + kg * 4;
    const int idx = r16 * DD + (c4 ^ swzS);
    uint2v xch = *(const uint2v*)&Yb[idx];
    unsigned int lo = xch[0], hi = xch[1];
    float y0 = bf2f((unsigned short)(lo & 0xffffu)) + g_reg * acc[nt][0];
    float y1 = bf2f((unsigned short)(lo >> 16))     + g_reg * acc[nt][1];
    float y2 = bf2f((unsigned short)(hi & 0xffffu)) + g_reg * acc[nt][2];
    float y3 = bf2f((unsigned short)(hi >> 16))     + g_reg * acc[nt][3];
    psum += (y0 + y1) + (y2 + y3);
    psq  += (y0*y0 + y1*y1) + (y2*y2 + y3*y3);
    uint2v yp;
    yp[0] = (unsigned)f2bf(y0) | ((unsigned)f2bf(y1) << 16);
    yp[1] = (unsigned)f2bf(y2) | ((unsigned)f2bf(y3) << 16);
    *(uint2v*)&Yb[idx] = yp;
  }
  psum += __shfl_xor(psum, 16); psum += __shfl_xor(psum, 32);
  psq  += __shfl_xor(psq, 16);  psq  += __shfl_xor(psq, 32);
  if (kg == 0){ pp[w][r16] = psum; qq[w][r16] = psq; }
  __syncthreads();  // S3

  // ---- phase 4: final LN + contiguous fp32 stores ----
#pragma unroll
  for (int i = 0; i < 4; ++i){
    const int rr = w * 4 + i;
    const float sm = pp[0][rr] + pp[1][rr] + pp[2][rr] + pp[3][rr];
    const float sq = qq[0][rr] + qq[1][rr] + qq[2][rr] + qq[3][rr];
    const float mu2 = sm * (1.f/DD);
    const float rs2 = rsqrtf(sq * (1.f/DD) - mu2*mu2 + 1e-5f);
    const int swz = (rr & 7) << 3;
#pragma unroll
    for (int h2 = 0; h2 < 2; ++h2){
      const int col = h2 * 256 + lane * 4;
      short4v yv = *(const short4v*)&Yb[rr * DD + (col ^ swz)];
      float la[4] = {lgh[h2].x, lgh[h2].y, lgh[h2].z, lgh[h2].w};
      float lb4[4] = {lbh[h2].x, lbh[h2].y, lbh[h2].z, lbh[h2].w};
      float4 o;
      o.x = (bf2f((unsigned short)yv[0]) - mu2) * rs2 * la[0] + lb4[0];
      o.y = (bf2f((unsigned short)yv[1]) - mu2) * rs2 * la[1] + lb4[1];
      o.z = (bf2f((unsigned short)yv[2]) - mu2) * rs2 * la[2] + lb4[2];
      o.w = (bf2f((unsigned short)yv[3]) - mu2) * rs2 * la[3] + lb4[3];
      *(float4*)(outF + (rowbase + rr) * DD + col) = o;
    }
  }
}

// ---------------- launch ----------------

extern "C" void kernel_launch(void* const* d_in, const int* in_sizes, int n_in,
                              void* d_out, int out_size, void* d_ws, size_t ws_size,
                              hipStream_t stream)
{
  const float* token = (const float*)d_in[0];
  const float* semb  = (const float*)d_in[1];
  const float* We    = (const float*)d_in[2];
  const float* be    = (const float*)d_in[3];
  const float* spos  = (const float*)d_in[4];
  const float* Wq    = (const float*)d_in[5];
  const float* bq    = (const float*)d_in[6];
  const float* Wk    = (const float*)d_in[7];
  const float* bk    = (const float*)d_in[8];
  const float* Wv    = (const float*)d_in[9];
  const float* bv    = (const float*)d_in[10];
  const float* Wo    = (const float*)d_in[11];
  const float* bo    = (const float*)d_in[12];
  const float* glng  = (const float*)d_in[13];
  const float* glnb  = (const float*)d_in[14];
  const float* Wg1   = (const float*)d_in[15];
  const float* bg1   = (const float*)d_in[16];
  const float* Wg2   = (const float*)d_in[17];
  const float* bg2   = (const float*)d_in[18];
  const float* lng   = (const float*)d_in[19];
  const float* lnb   = (const float*)d_in[20];

  char* ws = (char*)d_ws;
  float* e1             = (float*)(ws + 0);
  float* e2             = (float*)(ws + 512);
  float* spk            = (float*)(ws + 1024);     // 64 KB
  float* kb             = (float*)(ws + 65536 + 1024);
  float* vb             = (float*)(ws + 131072 + 1024);
  unsigned short* mS    = (unsigned short*)(ws + 196608);
  unsigned short* uS    = (unsigned short*)(ws + 458752);
  float* cArr           = (float*)(ws + 720896);
  unsigned short* wg1S  = (unsigned short*)(ws + 721920);

  float* outF  = (float*)d_out;
  float* outAW = outF + (size_t)NB * TN * DD;
  float* outG  = outAW + (size_t)NB * TN * 4;

  prep_spk<<<dim3(1281), dim3(256), 0, stream>>>(semb, We, be, spos, Wg1, glng, glnb, bg1,
                                                 spk, wg1S, e1, e2);
  prep_kv<<<dim3(1024), dim3(256), 0, stream>>>(spk, Wk, bk, Wv, bv, kb, vb);
  prep_mu<<<dim3(642), dim3(256), 0, stream>>>(kb, vb, Wq, bq, Wo, bo, mS, uS, cArr);
  fused_main<<<dim3(NB * TN / TT), dim3(256), 0, stream>>>(
      token, e1, e2, Wg2, bg2, lng, lnb,
      mS, uS, cArr, wg1S, outF, outAW, outG);
}

// Round 14
// 64.908 us; speedup vs baseline: 1.3382x; 1.2797x over previous
//
#include <hip/hip_runtime.h>
#include <hip/hip_bf16.h>
#include <stdint.h>

typedef __attribute__((ext_vector_type(8))) short short8;
typedef __attribute__((ext_vector_type(4))) short short4v;
typedef __attribute__((ext_vector_type(4))) float f32x4;
typedef __attribute__((ext_vector_type(2))) unsigned int uint2v;

#define DD 512
#define TT 32   // tokens per block (4 waves; 2 row-groups of 16)
#define TN 4096 // T
#define NB 8    // B

__device__ __forceinline__ unsigned short f2bf(float f){
  uint32_t u = __float_as_uint(f);
  u += 0x7FFFu + ((u >> 16) & 1u);
  return (unsigned short)(u >> 16);
}
__device__ __forceinline__ float bf2f(unsigned short h){
  return __uint_as_float(((uint32_t)h) << 16);
}

// ---------------- prep kernels (R13 structure — measured equal to R11) ----------------

__global__ void prep_spk(const float* __restrict__ se, const float* __restrict__ We,
                         const float* __restrict__ be, const float* __restrict__ spos,
                         const float* __restrict__ Wg1,
                         const float* __restrict__ glng, const float* __restrict__ glnb,
                         const float* __restrict__ bg1,
                         float* __restrict__ spk, unsigned short* __restrict__ wg1S,
                         float* __restrict__ e1, float* __restrict__ e2){
  int idx = blockIdx.x * 256 + threadIdx.x;   // 327808 used
  if (idx < 262144){
    int sub = idx & 15; int out = idx >> 4;
    int b = out & 7, od = out >> 3;
    const float* wr = We + (size_t)od * DD + sub * 4;
    const float* sb = se + b * DD + sub * 4;
    float acc = 0.f;
#pragma unroll
    for (int i = 0; i < 8; i++){
      float4 w = *(const float4*)(wr + i * 64);
      float4 x = *(const float4*)(sb + i * 64);
      acc += w.x * x.x + w.y * x.y + w.z * x.z + w.w * x.w;
    }
    acc += __shfl_xor(acc, 1); acc += __shfl_xor(acc, 2);
    acc += __shfl_xor(acc, 4); acc += __shfl_xor(acc, 8);
    if (sub == 0) spk[b * 2048 + od] = fmaxf(acc + be[od], 0.f) + spos[od];
  } else if (idx < 327680){
    int t = idx - 262144;               // t = col*512 + d
    int col = t >> 9, d = t & 511;
    int nt = col >> 4, c16 = col & 15;
    int kt = d >> 5, kgp = (d >> 3) & 3, e = d & 7;
    wg1S[(size_t)(nt * 16 + kt) * 512 + (kgp * 16 + c16) * 8 + e] = f2bf(Wg1[t] * glng[d]);
  } else if (idx < 327808){
    int col = idx - 327680;
    const float* wr = Wg1 + (size_t)col * DD;
    float a1 = 0.f, a2 = 0.f;
    for (int d = 0; d < DD; d += 4){
      float4 w  = *(const float4*)(wr + d);
      float4 gm = *(const float4*)(glng + d);
      float4 bt = *(const float4*)(glnb + d);
      a1 += w.x * gm.x + w.y * gm.y + w.z * gm.z + w.w * gm.w;
      a2 += w.x * bt.x + w.y * bt.y + w.z * bt.z + w.w * bt.w;
    }
    e1[col] = a1; e2[col] = a2 + bg1[col];
  }
}

__global__ void prep_kv(const float* __restrict__ spk, const float* __restrict__ Wk,
                        const float* __restrict__ bk, const float* __restrict__ Wv,
                        const float* __restrict__ bv, float* __restrict__ kb,
                        float* __restrict__ vb){
  int idx = blockIdx.x * 256 + threadIdx.x;   // 262144
  int sub = idx & 15; int out = idx >> 4;
  int hd = out >> 5; int r = out & 31; int b = r >> 2, s = r & 3;
  const float* sp  = spk + (b * 4 + s) * DD + sub * 4;
  const float* wkr = Wk + (size_t)hd * DD + sub * 4;
  const float* wvr = Wv + (size_t)hd * DD + sub * 4;
  float ak = 0.f, av = 0.f;
#pragma unroll
  for (int i = 0; i < 8; i++){
    float4 x  = *(const float4*)(sp + i * 64);
    float4 wk = *(const float4*)(wkr + i * 64);
    float4 wv = *(const float4*)(wvr + i * 64);
    ak += x.x * wk.x + x.y * wk.y + x.z * wk.z + x.w * wk.w;
    av += x.x * wv.x + x.y * wv.y + x.z * wv.z + x.w * wv.w;
  }
  ak += __shfl_xor(ak, 1); ak += __shfl_xor(ak, 2);
  ak += __shfl_xor(ak, 4); ak += __shfl_xor(ak, 8);
  av += __shfl_xor(av, 1); av += __shfl_xor(av, 2);
  av += __shfl_xor(av, 4); av += __shfl_xor(av, 8);
  if (sub == 0){
    kb[(b * 4 + s) * DD + hd] = ak + bk[hd];
    vb[(b * 4 + s) * DD + hd] = av + bv[hd];
  }
}

__global__ void prep_mu(const float* __restrict__ kb, const float* __restrict__ vb,
                        const float* __restrict__ Wq, const float* __restrict__ bq,
                        const float* __restrict__ Wo, const float* __restrict__ bo,
                        unsigned short* __restrict__ mS, unsigned short* __restrict__ uS,
                        float* __restrict__ cArr){
  int idx = blockIdx.x * 256 + threadIdx.x;     // 164096 used
  if (idx < 32768){
    int dc = idx & 127, j = (idx >> 7) & 31, b = idx >> 12;
    int h = j >> 2, s = j & 3;
    const int d0 = dc * 4;
    const float* kr = kb + (b * 4 + s) * DD + h * 64;
    const float* wqb = Wq + (size_t)(h * 64) * DD + d0;
    float4 acc = {0.f, 0.f, 0.f, 0.f};
#pragma unroll 8
    for (int dh = 0; dh < 64; ++dh){
      float4 w4 = *(const float4*)(wqb + (size_t)dh * DD);
      float kvv = kr[dh];
      acc.x += kvv * w4.x; acc.y += kvv * w4.y;
      acc.z += kvv * w4.z; acc.w += kvv * w4.w;
    }
    const int kt = d0 >> 5, kgp = (d0 >> 3) & 3, e0 = d0 & 7, half = j >> 4;
    unsigned short* dst = mS + (size_t)(b * 16 + kt) * 1024 + half * 512 +
                          (kgp * 16 + (j & 15)) * 8 + e0;
    short4v st;
    st[0] = (short)f2bf(acc.x); st[1] = (short)f2bf(acc.y);
    st[2] = (short)f2bf(acc.z); st[3] = (short)f2bf(acc.w);
    *(short4v*)dst = st;
  } else if (idx < 163840){
    int t = idx - 32768;
    int j = t & 31; int d = (t >> 5) & 511; int b = t >> 14;
    int h = j >> 2, s = j & 3;
    const float* vr = vb + (b * 4 + s) * DD + h * 64;
    const float* wo = Wo + (size_t)d * DD + h * 64;
    float acc = 0.f;
#pragma unroll 8
    for (int dh = 0; dh < 64; dh += 4){
      float4 v4 = *(const float4*)(vr + dh);
      float4 w4 = *(const float4*)(wo + dh);
      acc += v4.x * w4.x + v4.y * w4.y + v4.z * w4.z + v4.w * w4.w;
    }
    int nc = d >> 7, nt = (d >> 4) & 7, r16p = d & 15;
    int kgp = j >> 3, e = j & 7;
    uS[(size_t)(b * 32 + nc * 8 + nt) * 512 + (kgp * 16 + r16p) * 8 + e] =
        f2bf(acc + bo[d] * 0.125f);
  } else if (idx < 164096){
    int t = idx - 163840; int j = t & 31, b = t >> 5;
    int h = j >> 2, s = j & 3;
    const float* kr = kb + (b * 4 + s) * DD + h * 64;
    const float* bqp = bq + h * 64;
    float acc = 0.f;
    for (int dh = 0; dh < 64; dh++) acc += bqp[dh] * kr[dh];
    cArr[b * 32 + j] = acc;
  }
}

// ---------------- main fused kernel: 32 tokens (2 rgs), 4 waves, 4 blocks/CU ----------------

__global__ __launch_bounds__(256, 2) void fused_main(
    const float* __restrict__ xin,
    const float* __restrict__ e1v, const float* __restrict__ e2v,
    const float* __restrict__ wg2v, const float* __restrict__ bg2v,
    const float* __restrict__ lng, const float* __restrict__ lnb,
    const unsigned short* __restrict__ mS,
    const unsigned short* __restrict__ uS,
    const float* __restrict__ cArr,
    const unsigned short* __restrict__ wg1S,
    float* __restrict__ outF, float* __restrict__ outAW, float* __restrict__ outG)
{
  __shared__ __align__(16) unsigned short Yb[TT * DD];   // 32 KB x/y bf16 (swizzled)
  __shared__ __align__(16) unsigned short Wl[TT * 32];   // 2 KB softmax weights
  __shared__ float smu[TT], srs[TT];
  __shared__ float aws[2][TT * 4];
  __shared__ float gp[4][TT];
  __shared__ float pp[4][TT], qq[4][TT];

  const int tid  = threadIdx.x;
  const int w    = tid >> 6;
  const int lane = tid & 63;
  const int r16  = lane & 15;
  const int kg   = lane >> 4;
  const int bb   = blockIdx.x >> 7;           // 128 blocks per batch
  const int t0   = (blockIdx.x & 127) << 5;   // 32 tokens per block
  const size_t rowbase = (size_t)bb * TN + t0;
  const int swzS = (r16 & 7) << 3;

  // ---- phase 0: wave w loads rows w*8..w*8+7, convert + LN stats ----
  const float* xbase = xin + rowbase * DD;
#pragma unroll
  for (int i = 0; i < 8; ++i){
    const int rr = w * 8 + i;
    const int swz = (rr & 7) << 3;
    float s = 0.f, q = 0.f;
#pragma unroll
    for (int h2 = 0; h2 < 2; ++h2){
      const int col = h2 * 256 + lane * 4;
      float4 v4 = *(const float4*)(xbase + rr * DD + col);
      short4v pk;
      pk[0] = (short)f2bf(v4.x); pk[1] = (short)f2bf(v4.y);
      pk[2] = (short)f2bf(v4.z); pk[3] = (short)f2bf(v4.w);
      s += (v4.x + v4.y) + (v4.z + v4.w);
      q += (v4.x*v4.x + v4.y*v4.y) + (v4.z*v4.z + v4.w*v4.w);
      *(short4v*)&Yb[rr * DD + (col ^ swz)] = pk;
    }
#pragma unroll
    for (int off = 1; off < 64; off <<= 1){ s += __shfl_xor(s, off); q += __shfl_xor(q, off); }
    if (lane == 0){
      const float mu = s * (1.f/DD);
      smu[rr] = mu;
      srs[rr] = rsqrtf(q * (1.f/DD) - mu*mu + 1e-5f);
    }
  }
  __syncthreads();  // S1

  // ---- phase 1: each weight fragment feeds BOTH row-groups (2x amortization) ----
  const int half = w & 1;
  const int nt0  = w * 2;
  const unsigned short* mSp  = mS + (size_t)bb * 16384 + half * 512 + lane * 8;
  const unsigned short* wgp0 = wg1S + (size_t)(nt0 * 16) * 512 + lane * 8;
  const unsigned short* wgp1 = wgp0 + (size_t)16 * 512;
  f32x4 sa0 = {0.f,0.f,0.f,0.f}, sa1 = {0.f,0.f,0.f,0.f};
  f32x4 ga00 = {0.f,0.f,0.f,0.f}, ga01 = {0.f,0.f,0.f,0.f};
  f32x4 ga10 = {0.f,0.f,0.f,0.f}, ga11 = {0.f,0.f,0.f,0.f};
  if (w < 2){
#pragma unroll
    for (int kt = 0; kt < 16; ++kt){
      const int cofs = (kt*32 + kg*8) ^ swzS;
      short8 af0 = *(const short8*)&Yb[r16 * DD + cofs];
      short8 af1 = *(const short8*)&Yb[(16 + r16) * DD + cofs];
      short8 bm  = *(const short8*)(mSp + (size_t)kt * 1024);
      sa0 = __builtin_amdgcn_mfma_f32_16x16x32_bf16(af0, bm, sa0, 0, 0, 0);
      sa1 = __builtin_amdgcn_mfma_f32_16x16x32_bf16(af1, bm, sa1, 0, 0, 0);
      short8 wf0 = *(const short8*)(wgp0 + (size_t)kt * 512);
      short8 wf1 = *(const short8*)(wgp1 + (size_t)kt * 512);
      ga00 = __builtin_amdgcn_mfma_f32_16x16x32_bf16(wf0, af0, ga00, 0, 0, 0);
      ga01 = __builtin_amdgcn_mfma_f32_16x16x32_bf16(wf0, af1, ga01, 0, 0, 0);
      ga10 = __builtin_amdgcn_mfma_f32_16x16x32_bf16(wf1, af0, ga10, 0, 0, 0);
      ga11 = __builtin_amdgcn_mfma_f32_16x16x32_bf16(wf1, af1, ga11, 0, 0, 0);
    }
  } else {
#pragma unroll
    for (int kt = 0; kt < 16; ++kt){
      const int cofs = (kt*32 + kg*8) ^ swzS;
      short8 af0 = *(const short8*)&Yb[r16 * DD + cofs];
      short8 af1 = *(const short8*)&Yb[(16 + r16) * DD + cofs];
      short8 wf0 = *(const short8*)(wgp0 + (size_t)kt * 512);
      short8 wf1 = *(const short8*)(wgp1 + (size_t)kt * 512);
      ga00 = __builtin_amdgcn_mfma_f32_16x16x32_bf16(wf0, af0, ga00, 0, 0, 0);
      ga01 = __builtin_amdgcn_mfma_f32_16x16x32_bf16(wf0, af1, ga01, 0, 0, 0);
      ga10 = __builtin_amdgcn_mfma_f32_16x16x32_bf16(wf1, af0, ga10, 0, 0, 0);
      ga11 = __builtin_amdgcn_mfma_f32_16x16x32_bf16(wf1, af1, ga11, 0, 0, 0);
    }
  }

  // ---- early epilogue operand loads ----
  float4 e1c[2], e2c[2], w2c[2];
#pragma unroll
  for (int t = 0; t < 2; ++t){
    const int c4 = (nt0 + t) * 16 + kg * 4;
    e1c[t] = *(const float4*)(e1v + c4);
    e2c[t] = *(const float4*)(e2v + c4);
    w2c[t] = *(const float4*)(wg2v + c4);
  }
  float4 lgh[2], lbh[2];
#pragma unroll
  for (int h2 = 0; h2 < 2; ++h2){
    lgh[h2] = *(const float4*)(lng + h2*256 + lane*4);
    lbh[h2] = *(const float4*)(lnb + h2*256 + lane*4);
  }
  const float bg2s = bg2v[0];

  // ---- softmax epilogue (waves 0,1): both row-groups ----
  if (w < 2){
    const float cv = cArr[bb*32 + half*16 + r16];
#pragma unroll
    for (int rg = 0; rg < 2; ++rg){
      const f32x4 sa = rg ? sa1 : sa0;
#pragma unroll
      for (int r = 0; r < 4; ++r){
        float s0 = (sa[r] + cv) * 0.125f;
        float mx = fmaxf(s0, __shfl_xor(s0, 1)); mx = fmaxf(mx, __shfl_xor(mx, 2));
        float e0 = __expf(s0 - mx);
        float d0 = e0; d0 += __shfl_xor(d0, 1); d0 += __shfl_xor(d0, 2);
        float wv = e0 / d0;
        float t = wv; t += __shfl_xor(t, 4); t += __shfl_xor(t, 8);
        const int rw = rg * 16 + kg * 4 + r;
        Wl[rw * 32 + half * 16 + r16] = f2bf(wv);
        if ((lane & 12) == 0) aws[half][rw * 4 + (lane & 3)] = t;
      }
    }
  }

  // ---- gate partial (all waves): thread owns tokens r16 and 16+r16 ----
#pragma unroll
  for (int rg = 0; rg < 2; ++rg){
    const int tk = rg * 16 + r16;
    const float mu_t = smu[tk], rs_t = srs[tk];
    float part = 0.f;
#pragma unroll
    for (int t = 0; t < 2; ++t){
      const f32x4 ga = t ? (rg ? ga11 : ga10) : (rg ? ga01 : ga00);
      float ea[4] = {e1c[t].x, e1c[t].y, e1c[t].z, e1c[t].w};
      float eb[4] = {e2c[t].x, e2c[t].y, e2c[t].z, e2c[t].w};
      float wc[4] = {w2c[t].x, w2c[t].y, w2c[t].z, w2c[t].w};
#pragma unroll
      for (int r = 0; r < 4; ++r){
        float gv = rs_t * (ga[r] - mu_t * ea[r]) + eb[r];
        part += fmaxf(gv, 0.f) * wc[r];
      }
    }
    part += __shfl_xor(part, 16); part += __shfl_xor(part, 32);
    if (kg == 0) gp[w][tk] = part;
  }
  __syncthreads();  // S2

  // ---- outAW finalize (wave 2): 128 entries ----
  if (w == 2){
#pragma unroll
    for (int it = 0; it < 2; ++it){
      const int idx = it * 64 + lane;
      const int tok = idx >> 2, si = idx & 3;
      const float val = (aws[0][idx] + aws[1][idx]) * 0.125f;
      outAW[(rowbase + tok) * 4 + si] = val;
    }
  }
  // ---- gate finalize (2 tokens per thread) ----
  float g_loc[2];
#pragma unroll
  for (int rg = 0; rg < 2; ++rg){
    const int tk = rg * 16 + r16;
    const float gs = gp[0][tk] + gp[1][tk] + gp[2][tk] + gp[3][tk];
    g_loc[rg] = 1.f / (1.f + __expf(-(gs + bg2s)));
    if (w == 3 && kg == 0) outG[rowbase + tk] = g_loc[rg];
  }

  // ---- phase 3: uS fragments loaded once, reused for both row-groups ----
  const unsigned short* uSp = uS + (size_t)bb * 16384 + (size_t)(w * 8) * 512 + lane * 8;
  short8 uf[8];
#pragma unroll
  for (int nt = 0; nt < 8; ++nt) uf[nt] = *(const short8*)(uSp + (size_t)nt * 512);

#pragma unroll
  for (int rg = 0; rg < 2; ++rg){
    const int row = rg * 16 + r16;
    short8 awf = *(const short8*)&Wl[row * 32 + kg * 8];
    f32x4 acc[8];
#pragma unroll
    for (int nt = 0; nt < 8; ++nt){
      f32x4 z = {0.f,0.f,0.f,0.f};
      acc[nt] = __builtin_amdgcn_mfma_f32_16x16x32_bf16(uf[nt], awf, z, 0, 0, 0);
    }
    float psum = 0.f, psq = 0.f;
#pragma unroll
    for (int nt = 0; nt < 8; ++nt){
      const int c4 = w * 128 + nt * 16 + kg * 4;
      const int idx = row * DD + (c4 ^ swzS);
      uint2v xch = *(const uint2v*)&Yb[idx];
      unsigned int lo = xch[0], hi = xch[1];
      float y0 = bf2f((unsigned short)(lo & 0xffffu)) + g_loc[rg] * acc[nt][0];
      float y1 = bf2f((unsigned short)(lo >> 16))     + g_loc[rg] * acc[nt][1];
      float y2 = bf2f((unsigned short)(hi & 0xffffu)) + g_loc[rg] * acc[nt][2];
      float y3 = bf2f((unsigned short)(hi >> 16))     + g_loc[rg] * acc[nt][3];
      psum += (y0 + y1) + (y2 + y3);
      psq  += (y0*y0 + y1*y1) + (y2*y2 + y3*y3);
      uint2v yp;
      yp[0] = (unsigned)f2bf(y0) | ((unsigned)f2bf(y1) << 16);
      yp[1] = (unsigned)f2bf(y2) | ((unsigned)f2bf(y3) << 16);
      *(uint2v*)&Yb[idx] = yp;
    }
    psum += __shfl_xor(psum, 16); psum += __shfl_xor(psum, 32);
    psq  += __shfl_xor(psq, 16);  psq  += __shfl_xor(psq, 32);
    if (kg == 0){ pp[w][row] = psum; qq[w][row] = psq; }
  }
  __syncthreads();  // S3

  // ---- phase 4: final LN + contiguous fp32 stores (wave w: rows w*8..w*8+7) ----
#pragma unroll
  for (int i = 0; i < 8; ++i){
    const int rr = w * 8 + i;
    const float sm = pp[0][rr] + pp[1][rr] + pp[2][rr] + pp[3][rr];
    const float sq = qq[0][rr] + qq[1][rr] + qq[2][rr] + qq[3][rr];
    const float mu2 = sm * (1.f/DD);
    const float rs2 = rsqrtf(sq * (1.f/DD) - mu2*mu2 + 1e-5f);
    const int swz = (rr & 7) << 3;
#pragma unroll
    for (int h2 = 0; h2 < 2; ++h2){
      const int col = h2 * 256 + lane * 4;
      short4v yv = *(const short4v*)&Yb[rr * DD + (col ^ swz)];
      float la[4] = {lgh[h2].x, lgh[h2].y, lgh[h2].z, lgh[h2].w};
      float lb4[4] = {lbh[h2].x, lbh[h2].y, lbh[h2].z, lbh[h2].w};
      float4 o;
      o.x = (bf2f((unsigned short)yv[0]) - mu2) * rs2 * la[0] + lb4[0];
      o.y = (bf2f((unsigned short)yv[1]) - mu2) * rs2 * la[1] + lb4[1];
      o.z = (bf2f((unsigned short)yv[2]) - mu2) * rs2 * la[2] + lb4[2];
      o.w = (bf2f((unsigned short)yv[3]) - mu2) * rs2 * la[3] + lb4[3];
      *(float4*)(outF + (rowbase + rr) * DD + col) = o;
    }
  }
}

// ---------------- launch ----------------

extern "C" void kernel_launch(void* const* d_in, const int* in_sizes, int n_in,
                              void* d_out, int out_size, void* d_ws, size_t ws_size,
                              hipStream_t stream)
{
  const float* token = (const float*)d_in[0];
  const float* semb  = (const float*)d_in[1];
  const float* We    = (const float*)d_in[2];
  const float* be    = (const float*)d_in[3];
  const float* spos  = (const float*)d_in[4];
  const float* Wq    = (const float*)d_in[5];
  const float* bq    = (const float*)d_in[6];
  const float* Wk    = (const float*)d_in[7];
  const float* bk    = (const float*)d_in[8];
  const float* Wv    = (const float*)d_in[9];
  const float* bv    = (const float*)d_in[10];
  const float* Wo    = (const float*)d_in[11];
  const float* bo    = (const float*)d_in[12];
  const float* glng  = (const float*)d_in[13];
  const float* glnb  = (const float*)d_in[14];
  const float* Wg1   = (const float*)d_in[15];
  const float* bg1   = (const float*)d_in[16];
  const float* Wg2   = (const float*)d_in[17];
  const float* bg2   = (const float*)d_in[18];
  const float* lng   = (const float*)d_in[19];
  const float* lnb   = (const float*)d_in[20];

  char* ws = (char*)d_ws;
  float* e1             = (float*)(ws + 0);
  float* e2             = (float*)(ws + 512);
  float* spk            = (float*)(ws + 1024);
  float* kb             = (float*)(ws + 65536 + 1024);
  float* vb             = (float*)(ws + 131072 + 1024);
  unsigned short* mS    = (unsigned short*)(ws + 196608);
  unsigned short* uS    = (unsigned short*)(ws + 458752);
  float* cArr           = (float*)(ws + 720896);
  unsigned short* wg1S  = (unsigned short*)(ws + 721920);

  float* outF  = (float*)d_out;
  float* outAW = outF + (size_t)NB * TN * DD;
  float* outG  = outAW + (size_t)NB * TN * 4;

  prep_spk<<<dim3(1281), dim3(256), 0, stream>>>(semb, We, be, spos, Wg1, glng, glnb, bg1,
                                                 spk, wg1S, e1, e2);
  prep_kv<<<dim3(1024), dim3(256), 0, stream>>>(spk, Wk, bk, Wv, bv, kb, vb);
  prep_mu<<<dim3(642), dim3(256), 0, stream>>>(kb, vb, Wq, bq, Wo, bo, mS, uS, cArr);
  fused_main<<<dim3(NB * TN / TT), dim3(256), 0, stream>>>(
      token, e1, e2, Wg2, bg2, lng, lnb,
      mS, uS, cArr, wg1S, outF, outAW, outG);
}